// Round 2
// baseline (164.065 us; speedup 1.0000x reference)
//
#include <hip/hip_runtime.h>

// Problem constants (from reference): B=8, C=3, H=512, W=960
#define Bc 8
#define Cc 3
#define Hc 512
#define Wc 960
#define HWc (Hc * Wc)          // 491520
#define NPIX (Bc * HWc)        // 3932160
#define NTOT (Bc * Cc * HWc)   // 11796480

__global__ void zero_ws_kernel(double* ws) {
    if (threadIdx.x == 0 && blockIdx.x == 0) ws[0] = 0.0;
}

__global__ __launch_bounds__(256) void warp_loss_kernel(
    const float* __restrict__ disp,
    const float* __restrict__ left,
    const float* __restrict__ right,
    float* __restrict__ out,      // out[0]=loss (written later), out[1..] = img_warp_mask
    double* __restrict__ ws)
{
    const int idx = blockIdx.x * blockDim.x + threadIdx.x;  // grid sized exactly NPIX
    float local = 0.0f;

    {
        const int b   = idx / HWc;
        const int rem = idx - b * HWc;
        const int x   = rem % Wc;

        // disp[b,0,y,x] and disp[b,1,y,x]
        const size_t dbase = (size_t)b * 2 * HWc + rem;
        const float d0 = disp[dbase];
        const float d1 = disp[dbase + HWc];

        // vgrid = arange(W) - disp  (broadcast along W for BOTH channels)
        const float gx = (float)x - d0;
        const float gy = (float)x - d1;

        // reference treats gx,gy as normalized coords:
        const float ix = ((gx + 1.0f) * (float)Wc - 1.0f) * 0.5f;
        const float iy = ((gy + 1.0f) * (float)Hc - 1.0f) * 0.5f;

        const float x0f = floorf(ix);
        const float y0f = floorf(iy);
        const float x1f = x0f + 1.0f;
        const float y1f = y0f + 1.0f;
        const float wx1 = ix - x0f, wx0 = 1.0f - wx1;
        const float wy1 = iy - y0f, wy0 = 1.0f - wy1;

        const bool vx0 = (x0f >= 0.0f) & (x0f <= (float)(Wc - 1));
        const bool vx1 = (x1f >= 0.0f) & (x1f <= (float)(Wc - 1));
        const bool vy0 = (y0f >= 0.0f) & (y0f <= (float)(Hc - 1));
        const bool vy1 = (y1f >= 0.0f) & (y1f <= (float)(Hc - 1));

        const float m00 = (vx0 && vy0) ? 1.0f : 0.0f;
        const float m10 = (vx1 && vy0) ? 1.0f : 0.0f;
        const float m01 = (vx0 && vy1) ? 1.0f : 0.0f;
        const float m11 = (vx1 && vy1) ? 1.0f : 0.0f;

        const float w00 = wx0 * wy0, w10 = wx1 * wy0;
        const float w01 = wx0 * wy1, w11 = wx1 * wy1;

        // mask = bilinear sample of the all-ones image (zeros padding)
        const float maskv = m00 * w00 + m10 * w10 + m01 * w01 + m11 * w11;

        float* o = out + 1 + (size_t)b * Cc * HWc + rem;

        if (maskv < 0.999f) {
            // binarized mask == 0 -> output 0, zero loss contribution
            o[0]       = 0.0f;
            o[HWc]     = 0.0f;
            o[2 * HWc] = 0.0f;
        } else {
            const int x0 = min(max((int)x0f, 0), Wc - 1);
            const int x1 = min(max((int)x1f, 0), Wc - 1);
            const int y0 = min(max((int)y0f, 0), Hc - 1);
            const int y1 = min(max((int)y1f, 0), Hc - 1);

            const float* rb = right + (size_t)b * Cc * HWc;
            const float* lb = left  + (size_t)b * Cc * HWc;

            #pragma unroll
            for (int c = 0; c < Cc; ++c) {
                const float* rc = rb + c * HWc;
                const float v00 = (m00 != 0.0f) ? rc[y0 * Wc + x0] : 0.0f;
                const float v10 = (m10 != 0.0f) ? rc[y0 * Wc + x1] : 0.0f;
                const float v01 = (m01 != 0.0f) ? rc[y1 * Wc + x0] : 0.0f;
                const float v11 = (m11 != 0.0f) ? rc[y1 * Wc + x1] : 0.0f;
                const float val = v00 * w00 + v10 * w10 + v01 * w01 + v11 * w11;
                o[c * HWc] = val;
                local += fabsf(val - lb[c * HWc + rem]);
            }
        }
    }

    // wave (64-lane) reduction
    #pragma unroll
    for (int off = 32; off > 0; off >>= 1)
        local += __shfl_down(local, off, 64);

    __shared__ double wsum[4];
    const int wid = threadIdx.x >> 6;
    if ((threadIdx.x & 63) == 0) wsum[wid] = (double)local;
    __syncthreads();
    if (threadIdx.x == 0) {
        const double s = wsum[0] + wsum[1] + wsum[2] + wsum[3];
        if (s != 0.0) atomicAdd(ws, s);
    }
}

__global__ void finalize_kernel(const double* ws, float* out) {
    if (threadIdx.x == 0 && blockIdx.x == 0)
        out[0] = (float)(ws[0] / (double)NTOT);
}

extern "C" void kernel_launch(void* const* d_in, const int* in_sizes, int n_in,
                              void* d_out, int out_size, void* d_ws, size_t ws_size,
                              hipStream_t stream) {
    const float* disp  = (const float*)d_in[0];
    const float* left  = (const float*)d_in[1];
    const float* right = (const float*)d_in[2];
    float* out = (float*)d_out;
    double* ws = (double*)d_ws;

    zero_ws_kernel<<<1, 64, 0, stream>>>(ws);

    const int threads = 256;
    const int blocks = NPIX / threads;  // 3932160 / 256 = 15360 exactly
    warp_loss_kernel<<<blocks, threads, 0, stream>>>(disp, left, right, out, ws);

    finalize_kernel<<<1, 64, 0, stream>>>(ws, out);
}

// Round 4
// 150.576 us; speedup vs baseline: 1.0896x; 1.0896x over previous
//
#include <hip/hip_runtime.h>

// Problem constants (from reference): B=8, C=3, H=512, W=960
#define Bc 8
#define Cc 3
#define Hc 512
#define Wc 960
#define HWc (Hc * Wc)          // 491520
#define NPIX (Bc * HWc)        // 3932160
#define NTOT (Bc * Cc * HWc)   // 11796480
#define NBLK (NPIX / 256)      // 15360

__global__ __launch_bounds__(256) void warp_loss_kernel(
    const float* __restrict__ disp,
    const float* __restrict__ left,
    const float* __restrict__ right,
    float* __restrict__ out,      // out[0]=loss (written by finalize), out[1..] = img_warp_mask
    double* __restrict__ ws)      // ws[0..NBLK) = per-block partial |diff| sums
{
    const int idx = blockIdx.x * blockDim.x + threadIdx.x;  // grid sized exactly NPIX
    float local = 0.0f;

    {
        const int b   = idx / HWc;
        const int rem = idx - b * HWc;
        const int x   = rem % Wc;

        // disp[b,0,y,x] and disp[b,1,y,x]
        const size_t dbase = (size_t)b * 2 * HWc + rem;
        const float d0 = disp[dbase];
        const float d1 = disp[dbase + HWc];

        // vgrid = arange(W) - disp  (broadcast along W for BOTH channels)
        const float gx = (float)x - d0;
        const float gy = (float)x - d1;

        // reference treats gx,gy as normalized coords:
        const float ix = ((gx + 1.0f) * (float)Wc - 1.0f) * 0.5f;
        const float iy = ((gy + 1.0f) * (float)Hc - 1.0f) * 0.5f;

        const float x0f = floorf(ix);
        const float y0f = floorf(iy);
        const float x1f = x0f + 1.0f;
        const float y1f = y0f + 1.0f;
        const float wx1 = ix - x0f, wx0 = 1.0f - wx1;
        const float wy1 = iy - y0f, wy0 = 1.0f - wy1;

        const bool vx0 = (x0f >= 0.0f) & (x0f <= (float)(Wc - 1));
        const bool vx1 = (x1f >= 0.0f) & (x1f <= (float)(Wc - 1));
        const bool vy0 = (y0f >= 0.0f) & (y0f <= (float)(Hc - 1));
        const bool vy1 = (y1f >= 0.0f) & (y1f <= (float)(Hc - 1));

        const float m00 = (vx0 && vy0) ? 1.0f : 0.0f;
        const float m10 = (vx1 && vy0) ? 1.0f : 0.0f;
        const float m01 = (vx0 && vy1) ? 1.0f : 0.0f;
        const float m11 = (vx1 && vy1) ? 1.0f : 0.0f;

        const float w00 = wx0 * wy0, w10 = wx1 * wy0;
        const float w01 = wx0 * wy1, w11 = wx1 * wy1;

        // mask = bilinear sample of the all-ones image (zeros padding)
        const float maskv = m00 * w00 + m10 * w10 + m01 * w01 + m11 * w11;

        float* o = out + 1 + (size_t)b * Cc * HWc + rem;

        if (maskv < 0.999f) {
            // binarized mask == 0 -> output 0, zero loss contribution
            o[0]       = 0.0f;
            o[HWc]     = 0.0f;
            o[2 * HWc] = 0.0f;
        } else {
            const int x0 = min(max((int)x0f, 0), Wc - 1);
            const int x1 = min(max((int)x1f, 0), Wc - 1);
            const int y0 = min(max((int)y0f, 0), Hc - 1);
            const int y1 = min(max((int)y1f, 0), Hc - 1);

            const float* rb = right + (size_t)b * Cc * HWc;
            const float* lb = left  + (size_t)b * Cc * HWc;

            #pragma unroll
            for (int c = 0; c < Cc; ++c) {
                const float* rc = rb + c * HWc;
                const float v00 = (m00 != 0.0f) ? rc[y0 * Wc + x0] : 0.0f;
                const float v10 = (m10 != 0.0f) ? rc[y0 * Wc + x1] : 0.0f;
                const float v01 = (m01 != 0.0f) ? rc[y1 * Wc + x0] : 0.0f;
                const float v11 = (m11 != 0.0f) ? rc[y1 * Wc + x1] : 0.0f;
                const float val = v00 * w00 + v10 * w10 + v01 * w01 + v11 * w11;
                o[c * HWc] = val;
                local += fabsf(val - lb[c * HWc + rem]);
            }
        }
    }

    // wave (64-lane) reduction
    #pragma unroll
    for (int off = 32; off > 0; off >>= 1)
        local += __shfl_down(local, off, 64);

    __shared__ double wsum[4];
    const int wid = threadIdx.x >> 6;
    if ((threadIdx.x & 63) == 0) wsum[wid] = (double)local;
    __syncthreads();
    // contention-free: every block writes its own partial slot
    if (threadIdx.x == 0)
        ws[blockIdx.x] = wsum[0] + wsum[1] + wsum[2] + wsum[3];
}

__global__ __launch_bounds__(1024) void finalize_kernel(
    const double* __restrict__ ws, float* __restrict__ out)
{
    double s = 0.0;
    for (int i = threadIdx.x; i < NBLK; i += 1024)
        s += ws[i];

    #pragma unroll
    for (int off = 32; off > 0; off >>= 1)
        s += __shfl_down(s, off, 64);

    __shared__ double l[16];
    if ((threadIdx.x & 63) == 0) l[threadIdx.x >> 6] = s;
    __syncthreads();
    if (threadIdx.x == 0) {
        double t = 0.0;
        #pragma unroll
        for (int i = 0; i < 16; ++i) t += l[i];
        out[0] = (float)(t / (double)NTOT);
    }
}

extern "C" void kernel_launch(void* const* d_in, const int* in_sizes, int n_in,
                              void* d_out, int out_size, void* d_ws, size_t ws_size,
                              hipStream_t stream) {
    const float* disp  = (const float*)d_in[0];
    const float* left  = (const float*)d_in[1];
    const float* right = (const float*)d_in[2];
    float* out = (float*)d_out;
    double* ws = (double*)d_ws;

    warp_loss_kernel<<<NBLK, 256, 0, stream>>>(disp, left, right, out, ws);
    finalize_kernel<<<1, 1024, 0, stream>>>(ws, out);
}

// Round 11
// 144.667 us; speedup vs baseline: 1.1341x; 1.0408x over previous
//
#include <hip/hip_runtime.h>

// Problem constants (from reference): B=8, C=3, H=512, W=960
#define Bc 8
#define Cc 3
#define Hc 512
#define Wc 960
#define HWc (Hc * Wc)          // 491520
#define HW4 (HWc / 4)          // 122880 chunks of 4 pixels per batch
#define NPIX (Bc * HWc)        // 3932160
#define NTOT (Bc * Cc * HWc)   // 11796480
#define NBLK (NPIX / 4 / 256)  // 3840 blocks

// 16-byte vector with only 4-byte alignment guarantee (out+1 is 4B-aligned).
typedef float f4u __attribute__((ext_vector_type(4), aligned(4)));
typedef float f4a __attribute__((ext_vector_type(4), aligned(16)));

__global__ __launch_bounds__(256) void warp_loss_kernel(
    const float* __restrict__ disp,
    const float* __restrict__ left,
    const float* __restrict__ right,
    float* __restrict__ out,      // out[0]=loss (finalize), out[1..] = img_warp_mask
    double* __restrict__ ws)      // ws[0..NBLK) per-block partials
{
    const int tid  = blockIdx.x * blockDim.x + threadIdx.x;   // grid = NPIX/4 threads
    const int b    = tid / HW4;
    const int rem4 = tid - b * HW4;
    const int pix  = rem4 * 4;          // first pixel of this thread's chunk
    const int x    = pix % Wc;          // Wc%4==0 -> chunk never straddles a row

    // disp[b,0,y,x..x+3] and disp[b,1,y,x..x+3] — 16B aligned
    const size_t dbase = (size_t)b * 2 * HWc + pix;
    const f4a d0v = *(const f4a*)(disp + dbase);
    const f4a d1v = *(const f4a*)(disp + dbase + HWc);

    float v0[4], v1[4], v2[4];
    float local = 0.0f;

    const float* rb = right + (size_t)b * Cc * HWc;
    const float* lb = left  + (size_t)b * Cc * HWc;

    #pragma unroll
    for (int e = 0; e < 4; ++e) {
        const float d0 = d0v[e];
        const float d1 = d1v[e];
        const float xe = (float)(x + e);

        // vgrid = arange(W) - disp; sampler treats it as normalized coords
        const float gx = xe - d0;
        const float gy = xe - d1;
        const float ix = ((gx + 1.0f) * (float)Wc - 1.0f) * 0.5f;
        const float iy = ((gy + 1.0f) * (float)Hc - 1.0f) * 0.5f;

        const float x0f = floorf(ix);
        const float y0f = floorf(iy);
        const float x1f = x0f + 1.0f;
        const float y1f = y0f + 1.0f;
        const float wx1 = ix - x0f, wx0 = 1.0f - wx1;
        const float wy1 = iy - y0f, wy0 = 1.0f - wy1;

        const bool vx0 = (x0f >= 0.0f) & (x0f <= (float)(Wc - 1));
        const bool vx1 = (x1f >= 0.0f) & (x1f <= (float)(Wc - 1));
        const bool vy0 = (y0f >= 0.0f) & (y0f <= (float)(Hc - 1));
        const bool vy1 = (y1f >= 0.0f) & (y1f <= (float)(Hc - 1));

        const float m00 = (vx0 && vy0) ? 1.0f : 0.0f;
        const float m10 = (vx1 && vy0) ? 1.0f : 0.0f;
        const float m01 = (vx0 && vy1) ? 1.0f : 0.0f;
        const float m11 = (vx1 && vy1) ? 1.0f : 0.0f;

        const float w00 = wx0 * wy0, w10 = wx1 * wy0;
        const float w01 = wx0 * wy1, w11 = wx1 * wy1;

        const float maskv = m00 * w00 + m10 * w10 + m01 * w01 + m11 * w11;

        if (maskv < 0.999f) {
            v0[e] = 0.0f; v1[e] = 0.0f; v2[e] = 0.0f;
        } else {
            const int x0 = min(max((int)x0f, 0), Wc - 1);
            const int x1 = min(max((int)x1f, 0), Wc - 1);
            const int y0 = min(max((int)y0f, 0), Hc - 1);
            const int y1 = min(max((int)y1f, 0), Hc - 1);
            const int rem = pix + e;

            #pragma unroll
            for (int c = 0; c < Cc; ++c) {
                const float* rc = rb + c * HWc;
                const float s00 = (m00 != 0.0f) ? rc[y0 * Wc + x0] : 0.0f;
                const float s10 = (m10 != 0.0f) ? rc[y0 * Wc + x1] : 0.0f;
                const float s01 = (m01 != 0.0f) ? rc[y1 * Wc + x0] : 0.0f;
                const float s11 = (m11 != 0.0f) ? rc[y1 * Wc + x1] : 0.0f;
                const float val = s00 * w00 + s10 * w10 + s01 * w01 + s11 * w11;
                if (c == 0) v0[e] = val;
                if (c == 1) v1[e] = val;
                if (c == 2) v2[e] = val;
                local += fabsf(val - lb[c * HWc + rem]);
            }
        }
    }

    // vector stores: out+1 is 4B-aligned; f4u carries align(4)
    float* o = out + 1 + (size_t)b * Cc * HWc + pix;
    *(f4u*)(o)           = (f4u){v0[0], v0[1], v0[2], v0[3]};
    *(f4u*)(o + HWc)     = (f4u){v1[0], v1[1], v1[2], v1[3]};
    *(f4u*)(o + 2 * HWc) = (f4u){v2[0], v2[1], v2[2], v2[3]};

    // wave (64-lane) reduction
    #pragma unroll
    for (int off = 32; off > 0; off >>= 1)
        local += __shfl_down(local, off, 64);

    __shared__ double wsum[4];
    const int wid = threadIdx.x >> 6;
    if ((threadIdx.x & 63) == 0) wsum[wid] = (double)local;
    __syncthreads();
    if (threadIdx.x == 0)
        ws[blockIdx.x] = wsum[0] + wsum[1] + wsum[2] + wsum[3];
}

__global__ __launch_bounds__(1024) void finalize_kernel(
    const double* __restrict__ ws, float* __restrict__ out)
{
    double s = 0.0;
    for (int i = threadIdx.x; i < NBLK; i += 1024)
        s += ws[i];

    #pragma unroll
    for (int off = 32; off > 0; off >>= 1)
        s += __shfl_down(s, off, 64);

    __shared__ double l[16];
    if ((threadIdx.x & 63) == 0) l[threadIdx.x >> 6] = s;
    __syncthreads();
    if (threadIdx.x == 0) {
        double t = 0.0;
        #pragma unroll
        for (int i = 0; i < 16; ++i) t += l[i];
        out[0] = (float)(t / (double)NTOT);
    }
}

extern "C" void kernel_launch(void* const* d_in, const int* in_sizes, int n_in,
                              void* d_out, int out_size, void* d_ws, size_t ws_size,
                              hipStream_t stream) {
    const float* disp  = (const float*)d_in[0];
    const float* left  = (const float*)d_in[1];
    const float* right = (const float*)d_in[2];
    float* out = (float*)d_out;
    double* ws = (double*)d_ws;

    warp_loss_kernel<<<NBLK, 256, 0, stream>>>(disp, left, right, out, ws);
    finalize_kernel<<<1, 1024, 0, stream>>>(ws, out);
}